// Round 3
// baseline (1881.778 us; speedup 1.0000x reference)
//
#include <hip/hip_runtime.h>
#include <hip/hip_bf16.h>

typedef __hip_bfloat16 bf16;

#define B_    4
#define C_    192
#define NN    16384   // 128*128
#define HEADS 4
#define CHD   48
#define TOT   1152    // 576 qkv + 192 q_mut + 384 kv_mut

__device__ __forceinline__ float b2f(bf16 v) { return __bfloat162float(v); }

// ---------------------------------------------------------------------------
// K1: fused conv1x1 (K=192) + depthwise 3x3, zero 'SAME' padding.
// Inputs fp32. Output QT[b][1152][16384] bf16 (post-dwconv q,k,v,qm,km,vm).
// grid (64 spatial tiles, 72 channel groups of 16, 4 batch), block 256.
// Spatial tile: 32 wide x 8 high; halo tile 34x10 = 340 positions.
// ---------------------------------------------------------------------------
__global__ __launch_bounds__(256) void k1_conv_dw(
    const float* __restrict__ x, const float* __restrict__ xh,
    const float* __restrict__ qkv_w, const float* __restrict__ qkv_dw,
    const float* __restrict__ qm_w,  const float* __restrict__ qm_dw,
    const float* __restrict__ kvm_w, const float* __restrict__ kvm_dw,
    bf16* __restrict__ QT)
{
    const int tile = blockIdx.x;          // 0..63
    const int g    = blockIdx.y;          // 0..71
    const int b    = blockIdx.z;
    const int tx   = (tile & 3) * 32;
    const int ty   = (tile >> 2) * 8;
    const int tid  = threadIdx.x;

    __shared__ float sW[16][192];
    __shared__ float sDW[16][9];
    __shared__ float sT[16][344];         // 340 used (34x10 halo)

    const float* src; const float* wmat; const float* dwmat; int row0;
    const int ch0 = g * 16;
    if (ch0 < 576)      { src = x;  wmat = qkv_w; dwmat = qkv_dw; row0 = ch0; }
    else if (ch0 < 768) { src = x;  wmat = qm_w;  dwmat = qm_dw;  row0 = ch0 - 576; }
    else                { src = xh; wmat = kvm_w; dwmat = kvm_dw; row0 = ch0 - 768; }

    for (int i = tid; i < 16 * 192; i += 256) {
        int r = i / 192, c = i % 192;
        sW[r][c] = wmat[(row0 + r) * 192 + c];
    }
    for (int i = tid; i < 16 * 9; i += 256)
        sDW[i / 9][i % 9] = dwmat[(row0 + i / 9) * 9 + i % 9];
    __syncthreads();

    const float* xb = src + (size_t)b * C_ * NN;

    // conv1x1 at every halo position
    for (int p = tid; p < 340; p += 256) {
        const int hy = p / 34, hx = p % 34;
        const int gy = ty + hy - 1, gx = tx + hx - 1;
        float acc[16];
        #pragma unroll
        for (int o = 0; o < 16; ++o) acc[o] = 0.f;
        if (gy >= 0 && gy < 128 && gx >= 0 && gx < 128) {
            const float* xp = xb + gy * 128 + gx;
            for (int c = 0; c < 192; ++c) {
                float xv = xp[c * NN];
                #pragma unroll
                for (int o = 0; o < 16; ++o) acc[o] += sW[o][c] * xv;
            }
        }
        #pragma unroll
        for (int o = 0; o < 16; ++o) sT[o][p] = acc[o];
    }
    __syncthreads();

    // depthwise 3x3 on the tile interior
    const int oy = tid >> 5, ox = tid & 31;
    const size_t outbase =
        ((size_t)b * TOT + ch0) * NN + (size_t)(ty + oy) * 128 + (tx + ox);
    #pragma unroll
    for (int o = 0; o < 16; ++o) {
        float s = 0.f;
        #pragma unroll
        for (int ky = 0; ky < 3; ++ky)
            #pragma unroll
            for (int kx = 0; kx < 3; ++kx)
                s += sDW[o][ky * 3 + kx] * sT[o][(oy + ky) * 34 + ox + kx];
        QT[outbase + (size_t)o * NN] = __float2bfloat16(s);
    }
}

// ---------------------------------------------------------------------------
// K2: L2 norms over n for q (cls0), k (cls1), q_mut (cls2), k_mut (cls3).
// grid (192, 4, 4), block 256. nrm[b][cls][192] fp32.
// ---------------------------------------------------------------------------
__global__ __launch_bounds__(256) void k2_norm(
    const bf16* __restrict__ QT, float* __restrict__ nrm)
{
    const int ch = blockIdx.x, cls = blockIdx.y, b = blockIdx.z;
    const int base = (cls == 0) ? 0 : (cls == 1) ? 192 : (cls == 2) ? 576 : 768;
    const bf16* p = QT + ((size_t)b * TOT + base + ch) * NN;
    float acc = 0.f;
    for (int i = threadIdx.x; i < NN; i += 256) {
        float v = b2f(p[i]);
        acc += v * v;
    }
    #pragma unroll
    for (int off = 32; off > 0; off >>= 1) acc += __shfl_down(acc, off);
    __shared__ float red[4];
    if ((threadIdx.x & 63) == 0) red[threadIdx.x >> 6] = acc;
    __syncthreads();
    if (threadIdx.x == 0)
        nrm[(b * 4 + cls) * 192 + ch] = sqrtf(red[0] + red[1] + red[2] + red[3]);
}

// ---------------------------------------------------------------------------
// K3: unnormalized Gram matrices G[t][b][h][48][48], K = 16384 split into 8
// chunks of 2048 with fp32 atomic combine. grid (8, t*4+h -> 8, 4), block 256.
// ---------------------------------------------------------------------------
__global__ __launch_bounds__(256) void k3_gram(
    const bf16* __restrict__ QT, float* __restrict__ G)
{
    const int chunk = blockIdx.x;
    const int t = blockIdx.y >> 2, h = blockIdx.y & 3;
    const int b = blockIdx.z;
    const int qch = (t == 0 ? 0 : 576) + h * CHD;
    const int kch = (t == 0 ? 192 : 768) + h * CHD;
    const bf16* qp = QT + ((size_t)b * TOT + qch) * NN;
    const bf16* kp = QT + ((size_t)b * TOT + kch) * NN;

    __shared__ float sQ[48][65];
    __shared__ float sK[48][65];

    const int tid = threadIdx.x;
    const int c0 = (tid >> 4) * 3, d0 = (tid & 15) * 3;
    float acc[3][3] = {};
    const int n0 = chunk * 2048;

    for (int nt = 0; nt < 2048; nt += 64) {
        __syncthreads();
        for (int i = tid; i < 48 * 64; i += 256) {
            int c = i >> 6, j = i & 63;
            sQ[c][j] = b2f(qp[c * NN + n0 + nt + j]);
            sK[c][j] = b2f(kp[c * NN + n0 + nt + j]);
        }
        __syncthreads();
        for (int j = 0; j < 64; ++j) {
            float qv[3], kv[3];
            #pragma unroll
            for (int i = 0; i < 3; ++i) { qv[i] = sQ[c0 + i][j]; kv[i] = sK[d0 + i][j]; }
            #pragma unroll
            for (int i = 0; i < 3; ++i)
                #pragma unroll
                for (int jj = 0; jj < 3; ++jj) acc[i][jj] += qv[i] * kv[jj];
        }
    }
    float* Gp = G + (((size_t)t * 4 + b) * 4 + h) * 48 * 48;
    #pragma unroll
    for (int i = 0; i < 3; ++i)
        #pragma unroll
        for (int jj = 0; jj < 3; ++jj)
            atomicAdd(&Gp[(c0 + i) * 48 + d0 + jj], acc[i][jj]);
}

// ---------------------------------------------------------------------------
// K4: scale by temperature/(|q||k|), softmax over d, then fold proj:
//   M[t][b][o][h*48+d] = sum_c proj_w[o][t*192 + h*48 + c] * attn[c][d]
// grid (4 h, 2 t, 4 b), block 256. proj_w/temps are fp32.
// ---------------------------------------------------------------------------
__global__ __launch_bounds__(256) void k4_softmax_m(
    const float* __restrict__ G, const float* __restrict__ nrm,
    const float* __restrict__ proj_w, const float* __restrict__ tq,
    const float* __restrict__ tm, float* __restrict__ M)
{
    const int h = blockIdx.x, t = blockIdx.y, b = blockIdx.z;
    const float* Gp = G + (((size_t)t * 4 + b) * 4 + h) * 2304;
    __shared__ float sA[48][49];
    const int tid = threadIdx.x;

    if (tid < 48) {
        const int c = tid;
        const int clsq = (t == 0) ? 0 : 2, clsk = (t == 0) ? 1 : 3;
        const float nq = fmaxf(nrm[(b * 4 + clsq) * 192 + h * 48 + c], 1e-12f);
        const float tmp = (t == 0 ? tq[h] : tm[h]);
        float L[48];
        float mx = -1e30f;
        for (int d = 0; d < 48; ++d) {
            float nk = fmaxf(nrm[(b * 4 + clsk) * 192 + h * 48 + d], 1e-12f);
            L[d] = Gp[c * 48 + d] * tmp / (nq * nk);
            mx = fmaxf(mx, L[d]);
        }
        float sum = 0.f;
        for (int d = 0; d < 48; ++d) { L[d] = expf(L[d] - mx); sum += L[d]; }
        const float inv = 1.f / sum;
        for (int d = 0; d < 48; ++d) sA[c][d] = L[d] * inv;
    }
    __syncthreads();

    for (int idx = tid; idx < 192 * 48; idx += 256) {
        const int o = idx / 48, d = idx % 48;
        const float* pw = proj_w + o * 384 + t * 192 + h * 48;
        float s = 0.f;
        for (int c = 0; c < 48; ++c) s += pw[c] * sA[c][d];
        M[(((size_t)t * 4 + b) * 192 + o) * 192 + h * 48 + d] = s;
    }
}

// ---------------------------------------------------------------------------
// K5: final fused GEMM: out[b][o][n] = sum_d M1[b][o][d]*v[d][n]
//                                    + sum_d M2[b][o][d]*v_mut[d][n]
// grid (64 n-tiles of 256, 12 o-groups of 16, 4 b), block 256. out FP32.
// ---------------------------------------------------------------------------
__global__ __launch_bounds__(256) void k5_out(
    const bf16* __restrict__ QT, const float* __restrict__ M,
    float* __restrict__ out)
{
    const int nt = blockIdx.x, og = blockIdx.y, b = blockIdx.z;
    __shared__ float sM[16][384];
    const int tid = threadIdx.x;
    const int o0 = og * 16;
    for (int i = tid; i < 16 * 384; i += 256) {
        int r = i / 384, d = i % 384;
        int t = d / 192, dd = d % 192;
        sM[r][d] = M[(((size_t)t * 4 + b) * 192 + (o0 + r)) * 192 + dd];
    }
    __syncthreads();

    const int n = nt * 256 + tid;
    const bf16* vp  = QT + ((size_t)b * TOT + 384) * NN + n;   // v
    const bf16* vmp = QT + ((size_t)b * TOT + 960) * NN + n;   // v_mut
    float acc[16] = {};
    for (int d = 0; d < 192; ++d) {
        float v = b2f(vp[d * NN]);
        #pragma unroll
        for (int o = 0; o < 16; ++o) acc[o] += sM[o][d] * v;
    }
    for (int d = 0; d < 192; ++d) {
        float v = b2f(vmp[d * NN]);
        #pragma unroll
        for (int o = 0; o < 16; ++o) acc[o] += sM[o][192 + d] * v;
    }
    const size_t ob = ((size_t)b * C_ + o0) * NN + n;
    #pragma unroll
    for (int o = 0; o < 16; ++o)
        out[ob + (size_t)o * NN] = acc[o];
}

// ---------------------------------------------------------------------------
extern "C" void kernel_launch(void* const* d_in, const int* in_sizes, int n_in,
                              void* d_out, int out_size, void* d_ws, size_t ws_size,
                              hipStream_t stream)
{
    const float* x     = (const float*)d_in[0];
    const float* xh    = (const float*)d_in[1];
    const float* qkvw  = (const float*)d_in[2];
    const float* qkvdw = (const float*)d_in[3];
    const float* qmw   = (const float*)d_in[4];
    const float* qmdw  = (const float*)d_in[5];
    const float* kvmw  = (const float*)d_in[6];
    const float* kvmdw = (const float*)d_in[7];
    const float* projw = (const float*)d_in[8];
    const float* tq    = (const float*)d_in[9];
    const float* tm    = (const float*)d_in[10];
    float* out = (float*)d_out;

    char* ws = (char*)d_ws;
    bf16*  QT  = (bf16*)ws;
    size_t off = (size_t)B_ * TOT * NN * sizeof(bf16);            // 150,994,944
    float* nrm = (float*)(ws + off); off += (size_t)B_ * 4 * 192 * 4;
    float* G   = (float*)(ws + off); off += (size_t)2 * B_ * HEADS * 48 * 48 * 4;
    float* M   = (float*)(ws + off); off += (size_t)2 * B_ * 192 * 192 * 4;

    hipMemsetAsync(G, 0, (size_t)2 * B_ * HEADS * 48 * 48 * 4, stream);

    k1_conv_dw<<<dim3(64, 72, B_), 256, 0, stream>>>(
        x, xh, qkvw, qkvdw, qmw, qmdw, kvmw, kvmdw, QT);
    k2_norm<<<dim3(192, 4, B_), 256, 0, stream>>>(QT, nrm);
    k3_gram<<<dim3(8, 8, B_), 256, 0, stream>>>(QT, G);
    k4_softmax_m<<<dim3(4, 2, B_), 256, 0, stream>>>(G, nrm, projw, tq, tm, M);
    k5_out<<<dim3(64, 12, B_), 256, 0, stream>>>(QT, M, out);
}

// Round 4
// 1173.897 us; speedup vs baseline: 1.6030x; 1.6030x over previous
//
#include <hip/hip_runtime.h>
#include <hip/hip_bf16.h>

typedef __hip_bfloat16 bf16;
using short8  = __attribute__((ext_vector_type(8))) short;
using float4_ = __attribute__((ext_vector_type(4))) float;

#define B_    4
#define C_    192
#define NN    16384   // 128*128
#define HEADS 4
#define CHD   48
#define TOT   1152    // 576 qkv + 192 q_mut + 384 kv_mut

__device__ __forceinline__ float b2f(bf16 v) { return __bfloat162float(v); }

// ---------------------------------------------------------------------------
// kprep_w: concat+cast 1x1 weights -> Wb[1152][192] bf16.
// Row order qkv(576) | q_mut(192) | kv_mut(384) == QT channel order.
// ---------------------------------------------------------------------------
__global__ __launch_bounds__(256) void kprep_w(
    const float* __restrict__ qkv_w, const float* __restrict__ qm_w,
    const float* __restrict__ kvm_w, bf16* __restrict__ Wb)
{
    int i = blockIdx.x * 256 + threadIdx.x;          // 1152*192 = 221184
    if (i >= TOT * C_) return;
    int r = i / C_, c = i % C_;
    float v = (r < 576) ? qkv_w[r * C_ + c]
            : (r < 768) ? qm_w[(r - 576) * C_ + c]
                        : kvm_w[(r - 768) * C_ + c];
    Wb[i] = __float2bfloat16(v);
}

// ---------------------------------------------------------------------------
// kprep_x: per-batch transpose+cast x / x_hidden -> Xt[2][16384][192] bf16.
// grid (512 n-tiles, 6 c-tiles, 2 src), block 256, 32x32 LDS tile.
// ---------------------------------------------------------------------------
__global__ __launch_bounds__(256) void kprep_x(
    const float* __restrict__ x, const float* __restrict__ xh,
    int b, bf16* __restrict__ Xt)
{
    const int src = blockIdx.z;
    const float* in = (src == 0 ? x : xh) + (size_t)b * C_ * NN;
    bf16* outp = Xt + (size_t)src * NN * C_;
    const int n0 = blockIdx.x * 32, c0 = blockIdx.y * 32;
    __shared__ float t[32][33];
    const int tid = threadIdx.x;
    const int ln = tid & 31, lc = tid >> 5;          // 8 c-rows per iter
    #pragma unroll
    for (int it = 0; it < 4; ++it)
        t[lc + it * 8][ln] = in[(size_t)(c0 + lc + it * 8) * NN + n0 + ln];
    __syncthreads();
    const int lc2 = tid & 31, ln2 = tid >> 5;
    #pragma unroll
    for (int it = 0; it < 4; ++it)
        outp[(size_t)(n0 + ln2 + it * 8) * C_ + c0 + lc2] =
            __float2bfloat16(t[lc2][ln2 + it * 8]);
}

// ---------------------------------------------------------------------------
// kgemm: per-batch Y[1152][16384] = Wb[1152][192] x X[192][16384], bf16 MFMA.
// grid (128 n-tiles, 18 m-tiles), block 256 (4 waves, each 32m x 64n).
// A-frag: lane m=lane&15, k consecutive; B-frag: lane n=lane&15, k consec
// (from Xt[n][c]). K=192 in three 64-chunks via LDS.
// ---------------------------------------------------------------------------
__global__ __launch_bounds__(256) void kgemm(
    const bf16* __restrict__ Wb, const bf16* __restrict__ Xt,
    bf16* __restrict__ Y)
{
    const int nt0 = blockIdx.x * 128;
    const int mt0 = blockIdx.y * 64;
    const int tid = threadIdx.x;
    // rows 0..767 come from x (src 0), 768..1151 from x_hidden (src 1)
    const bf16* Xs = Xt + (mt0 >= 768 ? (size_t)NN * C_ : 0);

    __shared__ short sA[64][72];    // 72-pad: frag b128 reads conflict-free
    __shared__ short sB[128][72];

    const int wave = tid >> 6, lane = tid & 63;
    const int mw = (wave & 1) * 32, nw = (wave >> 1) * 64;
    const int lm = lane & 15, lq = lane >> 4;

    float4_ acc[2][4];
    #pragma unroll
    for (int i = 0; i < 2; ++i)
        #pragma unroll
        for (int j = 0; j < 4; ++j)
            acc[i][j] = (float4_){0.f, 0.f, 0.f, 0.f};

    for (int kc = 0; kc < 192; kc += 64) {
        __syncthreads();
        {   // stage A: 64 rows x 64 k (16B per thread-slot)
            int r = tid >> 3, c8 = (tid & 7) * 8;
            #pragma unroll
            for (int it = 0; it < 2; ++it, r += 32)
                *(short8*)&sA[r][c8] =
                    *(const short8*)&Wb[(size_t)(mt0 + r) * C_ + kc + c8];
        }
        {   // stage B: 128 rows x 64 k
            int r = tid >> 3, c8 = (tid & 7) * 8;
            #pragma unroll
            for (int it = 0; it < 4; ++it, r += 32)
                *(short8*)&sB[r][c8] =
                    *(const short8*)&Xs[(size_t)(nt0 + r) * C_ + kc + c8];
        }
        __syncthreads();
        #pragma unroll
        for (int kk = 0; kk < 64; kk += 32) {
            short8 af[2], bfr[4];
            const int ko = kk + lq * 8;
            #pragma unroll
            for (int i = 0; i < 2; ++i)
                af[i] = *(const short8*)&sA[mw + i * 16 + lm][ko];
            #pragma unroll
            for (int j = 0; j < 4; ++j)
                bfr[j] = *(const short8*)&sB[nw + j * 16 + lm][ko];
            #pragma unroll
            for (int i = 0; i < 2; ++i)
                #pragma unroll
                for (int j = 0; j < 4; ++j)
                    acc[i][j] = __builtin_amdgcn_mfma_f32_16x16x32_bf16(
                        af[i], bfr[j], acc[i][j], 0, 0, 0);
        }
    }
    // D layout: col = lane&15 (n), row = lq*4 + r (m)  [m89-verified]
    #pragma unroll
    for (int i = 0; i < 2; ++i)
        #pragma unroll
        for (int j = 0; j < 4; ++j) {
            const int n = nt0 + nw + j * 16 + lm;
            #pragma unroll
            for (int r = 0; r < 4; ++r) {
                const int m = mt0 + mw + i * 16 + lq * 4 + r;
                Y[(size_t)m * NN + n] = __float2bfloat16(acc[i][j][r]);
            }
        }
}

// ---------------------------------------------------------------------------
// kdw: per-batch depthwise 3x3 (SAME, zero pad) Y -> QT[b]. grid (64, 1152).
// ---------------------------------------------------------------------------
__global__ __launch_bounds__(256) void kdw(
    const bf16* __restrict__ Y,
    const float* __restrict__ qkv_dw, const float* __restrict__ qm_dw,
    const float* __restrict__ kvm_dw, int b, bf16* __restrict__ QT)
{
    const int ch = blockIdx.y;
    const int tile = blockIdx.x;
    const int x0 = (tile & 3) * 32, y0 = (tile >> 2) * 8;
    const int tid = threadIdx.x;
    const int xx = x0 + (tid & 31), yy = y0 + (tid >> 5);
    const float* dwp = (ch < 576) ? qkv_dw + (size_t)ch * 9
                     : (ch < 768) ? qm_dw + (size_t)(ch - 576) * 9
                                  : kvm_dw + (size_t)(ch - 768) * 9;
    const bf16* Yc = Y + (size_t)ch * NN;
    float s = 0.f;
    #pragma unroll
    for (int dy = -1; dy <= 1; ++dy)
        #pragma unroll
        for (int dx = -1; dx <= 1; ++dx) {
            const int gy = yy + dy, gx = xx + dx;
            const float v = (gy >= 0 && gy < 128 && gx >= 0 && gx < 128)
                          ? b2f(Yc[gy * 128 + gx]) : 0.f;
            s += dwp[(dy + 1) * 3 + (dx + 1)] * v;
        }
    QT[((size_t)b * TOT + ch) * NN + yy * 128 + xx] = __float2bfloat16(s);
}

// ---------------------------------------------------------------------------
// K2: L2 norms over n for q (cls0), k (cls1), q_mut (cls2), k_mut (cls3).
// ---------------------------------------------------------------------------
__global__ __launch_bounds__(256) void k2_norm(
    const bf16* __restrict__ QT, float* __restrict__ nrm)
{
    const int ch = blockIdx.x, cls = blockIdx.y, b = blockIdx.z;
    const int base = (cls == 0) ? 0 : (cls == 1) ? 192 : (cls == 2) ? 576 : 768;
    const bf16* p = QT + ((size_t)b * TOT + base + ch) * NN;
    float acc = 0.f;
    for (int i = threadIdx.x; i < NN; i += 256) {
        float v = b2f(p[i]);
        acc += v * v;
    }
    #pragma unroll
    for (int off = 32; off > 0; off >>= 1) acc += __shfl_down(acc, off);
    __shared__ float red[4];
    if ((threadIdx.x & 63) == 0) red[threadIdx.x >> 6] = acc;
    __syncthreads();
    if (threadIdx.x == 0)
        nrm[(b * 4 + cls) * 192 + ch] = sqrtf(red[0] + red[1] + red[2] + red[3]);
}

// ---------------------------------------------------------------------------
// K3: unnormalized Gram matrices G[t][b][h][48][48].
// ---------------------------------------------------------------------------
__global__ __launch_bounds__(256) void k3_gram(
    const bf16* __restrict__ QT, float* __restrict__ G)
{
    const int chunk = blockIdx.x;
    const int t = blockIdx.y >> 2, h = blockIdx.y & 3;
    const int b = blockIdx.z;
    const int qch = (t == 0 ? 0 : 576) + h * CHD;
    const int kch = (t == 0 ? 192 : 768) + h * CHD;
    const bf16* qp = QT + ((size_t)b * TOT + qch) * NN;
    const bf16* kp = QT + ((size_t)b * TOT + kch) * NN;

    __shared__ float sQ[48][65];
    __shared__ float sK[48][65];

    const int tid = threadIdx.x;
    const int c0 = (tid >> 4) * 3, d0 = (tid & 15) * 3;
    float acc[3][3] = {};
    const int n0 = chunk * 2048;

    for (int nt = 0; nt < 2048; nt += 64) {
        __syncthreads();
        for (int i = tid; i < 48 * 64; i += 256) {
            int c = i >> 6, j = i & 63;
            sQ[c][j] = b2f(qp[c * NN + n0 + nt + j]);
            sK[c][j] = b2f(kp[c * NN + n0 + nt + j]);
        }
        __syncthreads();
        for (int j = 0; j < 64; ++j) {
            float qv[3], kv[3];
            #pragma unroll
            for (int i = 0; i < 3; ++i) { qv[i] = sQ[c0 + i][j]; kv[i] = sK[d0 + i][j]; }
            #pragma unroll
            for (int i = 0; i < 3; ++i)
                #pragma unroll
                for (int jj = 0; jj < 3; ++jj) acc[i][jj] += qv[i] * kv[jj];
        }
    }
    float* Gp = G + (((size_t)t * 4 + b) * 4 + h) * 48 * 48;
    #pragma unroll
    for (int i = 0; i < 3; ++i)
        #pragma unroll
        for (int jj = 0; jj < 3; ++jj)
            atomicAdd(&Gp[(c0 + i) * 48 + d0 + jj], acc[i][jj]);
}

// ---------------------------------------------------------------------------
// K4: scale by temperature/(|q||k|), softmax over d, fold proj -> M.
// ---------------------------------------------------------------------------
__global__ __launch_bounds__(256) void k4_softmax_m(
    const float* __restrict__ G, const float* __restrict__ nrm,
    const float* __restrict__ proj_w, const float* __restrict__ tq,
    const float* __restrict__ tm, float* __restrict__ M)
{
    const int h = blockIdx.x, t = blockIdx.y, b = blockIdx.z;
    const float* Gp = G + (((size_t)t * 4 + b) * 4 + h) * 2304;
    __shared__ float sA[48][49];
    const int tid = threadIdx.x;

    if (tid < 48) {
        const int c = tid;
        const int clsq = (t == 0) ? 0 : 2, clsk = (t == 0) ? 1 : 3;
        const float nq = fmaxf(nrm[(b * 4 + clsq) * 192 + h * 48 + c], 1e-12f);
        const float tmp = (t == 0 ? tq[h] : tm[h]);
        float L[48];
        float mx = -1e30f;
        for (int d = 0; d < 48; ++d) {
            float nk = fmaxf(nrm[(b * 4 + clsk) * 192 + h * 48 + d], 1e-12f);
            L[d] = Gp[c * 48 + d] * tmp / (nq * nk);
            mx = fmaxf(mx, L[d]);
        }
        float sum = 0.f;
        for (int d = 0; d < 48; ++d) { L[d] = expf(L[d] - mx); sum += L[d]; }
        const float inv = 1.f / sum;
        for (int d = 0; d < 48; ++d) sA[c][d] = L[d] * inv;
    }
    __syncthreads();

    for (int idx = tid; idx < 192 * 48; idx += 256) {
        const int o = idx / 48, d = idx % 48;
        const float* pw = proj_w + o * 384 + t * 192 + h * 48;
        float s = 0.f;
        for (int c = 0; c < 48; ++c) s += pw[c] * sA[c][d];
        M[(((size_t)t * 4 + b) * 192 + o) * 192 + h * 48 + d] = s;
    }
}

// ---------------------------------------------------------------------------
// K5: out[b][o][n] = sum_d M1[b][o][d]*v[d][n] + sum_d M2[b][o][d]*vm[d][n].
// out fp32.
// ---------------------------------------------------------------------------
__global__ __launch_bounds__(256) void k5_out(
    const bf16* __restrict__ QT, const float* __restrict__ M,
    float* __restrict__ out)
{
    const int nt = blockIdx.x, og = blockIdx.y, b = blockIdx.z;
    __shared__ float sM[16][384];
    const int tid = threadIdx.x;
    const int o0 = og * 16;
    for (int i = tid; i < 16 * 384; i += 256) {
        int r = i / 384, d = i % 384;
        int t = d / 192, dd = d % 192;
        sM[r][d] = M[(((size_t)t * 4 + b) * 192 + (o0 + r)) * 192 + dd];
    }
    __syncthreads();

    const int n = nt * 256 + tid;
    const bf16* vp  = QT + ((size_t)b * TOT + 384) * NN + n;   // v
    const bf16* vmp = QT + ((size_t)b * TOT + 960) * NN + n;   // v_mut
    float acc[16] = {};
    for (int d = 0; d < 192; ++d) {
        float v = b2f(vp[d * NN]);
        #pragma unroll
        for (int o = 0; o < 16; ++o) acc[o] += sM[o][d] * v;
    }
    for (int d = 0; d < 192; ++d) {
        float v = b2f(vmp[d * NN]);
        #pragma unroll
        for (int o = 0; o < 16; ++o) acc[o] += sM[o][192 + d] * v;
    }
    const size_t ob = ((size_t)b * C_ + o0) * NN + n;
    #pragma unroll
    for (int o = 0; o < 16; ++o)
        out[ob + (size_t)o * NN] = acc[o];
}

// ---------------------------------------------------------------------------
extern "C" void kernel_launch(void* const* d_in, const int* in_sizes, int n_in,
                              void* d_out, int out_size, void* d_ws, size_t ws_size,
                              hipStream_t stream)
{
    const float* x     = (const float*)d_in[0];
    const float* xh    = (const float*)d_in[1];
    const float* qkvw  = (const float*)d_in[2];
    const float* qkvdw = (const float*)d_in[3];
    const float* qmw   = (const float*)d_in[4];
    const float* qmdw  = (const float*)d_in[5];
    const float* kvmw  = (const float*)d_in[6];
    const float* kvmdw = (const float*)d_in[7];
    const float* projw = (const float*)d_in[8];
    const float* tq    = (const float*)d_in[9];
    const float* tm    = (const float*)d_in[10];
    float* out = (float*)d_out;

    char* ws = (char*)d_ws;
    size_t off = 0;
    bf16*  QT = (bf16*)(ws + off);  off += (size_t)B_ * TOT * NN * 2;   // 151.0 MB
    bf16*  Y  = (bf16*)(ws + off);  off += (size_t)TOT * NN * 2;        //  37.7 MB
    bf16*  Xt = (bf16*)(ws + off);  off += (size_t)2 * NN * C_ * 2;     //  12.6 MB
    bf16*  Wb = (bf16*)(ws + off);  off += (size_t)TOT * C_ * 2;        //   0.44 MB
    float* nrm = (float*)(ws + off); off += (size_t)B_ * 4 * 192 * 4;
    float* G   = (float*)(ws + off); off += (size_t)2 * B_ * HEADS * 48 * 48 * 4;
    float* M   = (float*)(ws + off); off += (size_t)2 * B_ * 192 * 192 * 4;

    hipMemsetAsync(G, 0, (size_t)2 * B_ * HEADS * 48 * 48 * 4, stream);

    kprep_w<<<dim3((TOT * C_ + 255) / 256), 256, 0, stream>>>(qkvw, qmw, kvmw, Wb);

    for (int b = 0; b < B_; ++b) {
        kprep_x<<<dim3(512, 6, 2), 256, 0, stream>>>(x, xh, b, Xt);
        kgemm  <<<dim3(128, 18), 256, 0, stream>>>(Wb, Xt, Y);
        kdw    <<<dim3(64, 1152), 256, 0, stream>>>(Y, qkvdw, qmdw, kvmdw, b, QT);
    }

    k2_norm     <<<dim3(192, 4, B_), 256, 0, stream>>>(QT, nrm);
    k3_gram     <<<dim3(8, 8, B_), 256, 0, stream>>>(QT, G);
    k4_softmax_m<<<dim3(4, 2, B_), 256, 0, stream>>>(G, nrm, projw, tq, tm, M);
    k5_out      <<<dim3(64, 12, B_), 256, 0, stream>>>(QT, M, out);
}